// Round 2
// baseline (1026.011 us; speedup 1.0000x reference)
//
#include <hip/hip_runtime.h>

// Euclidean transformer layer, MI355X fp32 baseline.
// N=20000 nodes, E=200000 edges, F=132, heads: inv 4x33, ev 3x44.

#define NN 20000
#define NE 200000
#define FD 132
#define RB 32
#define EVD 15
#define KTOT 165   // 132 h-rows + 33 g-rows
#define TE 28      // edges per block in k_edge
#define KP 56      // K-partition rows staged in LDS at a time (56,56,53)

__device__ __forceinline__ float silu_f(float x) {
    return x / (1.0f + __expf(-x));
}

// ---------------- node projections: q/k/v_inv (4x33), q/k_ev (3x44) ----------
__global__ __launch_bounds__(256) void k_proj(
    const float* __restrict__ xin,
    const float* __restrict__ Wq, const float* __restrict__ Wk, const float* __restrict__ Wv,
    const float* __restrict__ Wqe, const float* __restrict__ Wke,
    float* __restrict__ qinv, float* __restrict__ kinv, float* __restrict__ vinv,
    float* __restrict__ qev, float* __restrict__ kev)
{
    __shared__ float xl[8][FD];
    const int t = threadIdx.x;
    const int n0 = blockIdx.x * 8;
    for (int idx = t; idx < 8 * FD; idx += 256) {
        int nl = idx / FD, j = idx - nl * FD;
        int n = n0 + nl;
        xl[nl][j] = (n < NN) ? xin[n * FD + j] : 0.0f;
    }
    __syncthreads();
    for (int idx = t; idx < 8 * FD; idx += 256) {
        int nl = idx / FD, j = idx - nl * FD;
        int n = n0 + nl;
        if (n >= NN) continue;
        // inv heads: 4 x 33. out[j] = sum_i W[H][i][jj] * x[H*33+i]
        {
            int H = j / 33, jj = j - H * 33;
            const float* xb = &xl[nl][H * 33];
            const float* wq = Wq + H * 1089 + jj;
            const float* wk = Wk + H * 1089 + jj;
            const float* wv = Wv + H * 1089 + jj;
            float aq = 0.f, ak = 0.f, av = 0.f;
            #pragma unroll
            for (int i = 0; i < 33; ++i) {
                float xv = xb[i];
                aq = fmaf(wq[i * 33], xv, aq);
                ak = fmaf(wk[i * 33], xv, ak);
                av = fmaf(wv[i * 33], xv, av);
            }
            qinv[n * FD + j] = aq; kinv[n * FD + j] = ak; vinv[n * FD + j] = av;
        }
        // ev heads: 3 x 44 on the SAME inv_features
        {
            int H = j / 44, jj = j - H * 44;
            const float* xb = &xl[nl][H * 44];
            const float* wq = Wqe + H * 1936 + jj;
            const float* wk = Wke + H * 1936 + jj;
            float aq = 0.f, ak = 0.f;
            #pragma unroll
            for (int i = 0; i < 44; ++i) {
                float xv = xb[i];
                aq = fmaf(wq[i * 44], xv, aq);
                ak = fmaf(wk[i * 44], xv, ak);
            }
            qev[n * FD + j] = aq; kev[n * FD + j] = ak;
        }
    }
}

// ---------------- per-edge SO(3) invariants of ev-diff ------------------------
__global__ __launch_bounds__(256) void k_evi(
    const float* __restrict__ ev, const int* __restrict__ snd,
    const int* __restrict__ rcv, float* __restrict__ evi)
{
    int e = blockIdx.x * 256 + threadIdx.x;
    if (e >= NE) return;
    int s = snd[e], r = rcv[e];
    const float* ps = &ev[s * EVD];
    const float* pr = &ev[r * EVD];
    float s0 = 0.f, s1 = 0.f, s2 = 0.f;
    #pragma unroll
    for (int m = 0; m < 3; ++m)  { float d = ps[m] - pr[m]; s0 = fmaf(d, d, s0); }
    #pragma unroll
    for (int m = 3; m < 8; ++m)  { float d = ps[m] - pr[m]; s1 = fmaf(d, d, s1); }
    #pragma unroll
    for (int m = 8; m < 15; ++m) { float d = ps[m] - pr[m]; s2 = fmaf(d, d, s2); }
    evi[e * 3 + 0] = s0; evi[e * 3 + 1] = s1; evi[e * 3 + 2] = s2;
}

// ---------------- fused edge kernel: filter GEMM + attention + scatter --------
// PATH 0: inv path (4 heads x 33, scatter 132/edge into d_inv)
// PATH 1: ev  path (3 heads x 44, scatter 15/edge into d_ev)
template<int PATH>
__global__ __launch_bounds__(256) void k_edge(
    const float* __restrict__ rbf, const float* __restrict__ evi,
    const int* __restrict__ snd, const int* __restrict__ rcv,
    const float* __restrict__ cut, const float* __restrict__ sh,
    const float* __restrict__ W1, const float* __restrict__ b1,
    const float* __restrict__ W2, const float* __restrict__ b2,
    const float* __restrict__ We1, const float* __restrict__ be1,
    const float* __restrict__ We2, const float* __restrict__ be2,
    const float* __restrict__ qt, const float* __restrict__ kt,
    const float* __restrict__ vt, float* __restrict__ dout)
{
    __shared__ __align__(16) float Wp[KP * FD];    // 29.6 KB, aliased as FW after GEMM
    __shared__ __align__(16) float HT[KTOT * TE];  // 18.5 KB, layout [i][e]
    __shared__ float rbl[TE * RB];
    __shared__ float evl[TE * 3];
    __shared__ int   sl[TE];
    __shared__ int   rl[TE];
    __shared__ float cl[TE];
    __shared__ float al[TE * 4];

    const int t = threadIdx.x;
    const int e0 = blockIdx.x * TE;

    // ---- stage per-edge inputs ----
    for (int idx = t; idx < TE * RB; idx += 256) {
        int e = idx >> 5;
        rbl[idx] = (e0 + e < NE) ? rbf[e0 * RB + idx] : 0.0f;
    }
    for (int idx = t; idx < TE * 3; idx += 256) {
        int e = idx / 3;
        evl[idx] = (e0 + e < NE) ? evi[e0 * 3 + idx] : 0.0f;
    }
    if (t < TE) {
        int eg = e0 + t;
        sl[t] = (eg < NE) ? snd[eg] : 0;
        rl[t] = (eg < NE) ? rcv[eg] : 0;
        cl[t] = (eg < NE) ? cut[eg] : 0.0f;
    }
    __syncthreads();

    // ---- Hext rows 0..131: h = silu(rbf @ W1 + b1) ----
    for (int idx = t; idx < TE * FD; idx += 256) {
        int e = idx / FD, i = idx - e * FD;
        float v = 0.0f;
        if (e0 + e < NE) {
            float a = b1[i];
            #pragma unroll
            for (int k = 0; k < RB; ++k)
                a = fmaf(rbl[e * RB + k], W1[k * FD + i], a);
            v = silu_f(a);
        }
        HT[i * TE + e] = v;
    }
    // ---- Hext rows 132..164: g = silu(evi @ We1 + be1) ----
    for (int idx = t; idx < TE * 33; idx += 256) {
        int e = idx / 33, ii = idx - e * 33;
        float v = 0.0f;
        if (e0 + e < NE) {
            float a = be1[ii];
            a = fmaf(evl[e * 3 + 0], We1[ii], a);
            a = fmaf(evl[e * 3 + 1], We1[33 + ii], a);
            a = fmaf(evl[e * 3 + 2], We1[66 + ii], a);
            v = silu_f(a);
        }
        HT[(FD + ii) * TE + e] = v;
    }

    // ---- main GEMM: fw[TE][132] = Hext[TE][165] @ Wcat[165][132] ----
    // thread (cg,rg): cols 4cg..4cg+3, edges 4rg..4rg+3 (231 active threads)
    const int cg = t % 33;
    const int rg = t / 33;
    const bool act = (t < 231);
    float ax0=0,ax1=0,ax2=0,ax3=0;
    float bx0=0,bx1=0,bx2=0,bx3=0;
    float cx0=0,cx1=0,cx2=0,cx3=0;
    float dx0=0,dx1=0,dx2=0,dx3=0;
    for (int part = 0; part < 3; ++part) {
        const int base = part * KP;
        const int rows = (KTOT - base < KP) ? (KTOT - base) : KP;
        __syncthreads();  // previous part's reads done before restage
        for (int idx = t; idx < rows * FD; idx += 256) {
            int q = idx / FD, cc = idx - q * FD;
            int rr = base + q;
            Wp[idx] = (rr < FD) ? W2[rr * FD + cc] : We2[(rr - FD) * FD + cc];
        }
        __syncthreads();
        if (act) {
            const float* wrow = &Wp[4 * cg];
            const float* hrow = &HT[base * TE + 4 * rg];
            #pragma unroll 4
            for (int i = 0; i < rows; ++i) {
                const float4 w = *(const float4*)(wrow + i * FD);
                const float4 h = *(const float4*)(hrow + i * TE);
                ax0 = fmaf(w.x, h.x, ax0); ax1 = fmaf(w.y, h.x, ax1);
                ax2 = fmaf(w.z, h.x, ax2); ax3 = fmaf(w.w, h.x, ax3);
                bx0 = fmaf(w.x, h.y, bx0); bx1 = fmaf(w.y, h.y, bx1);
                bx2 = fmaf(w.z, h.y, bx2); bx3 = fmaf(w.w, h.y, bx3);
                cx0 = fmaf(w.x, h.z, cx0); cx1 = fmaf(w.y, h.z, cx1);
                cx2 = fmaf(w.z, h.z, cx2); cx3 = fmaf(w.w, h.z, cx3);
                dx0 = fmaf(w.x, h.w, dx0); dx1 = fmaf(w.y, h.w, dx1);
                dx2 = fmaf(w.z, h.w, dx2); dx3 = fmaf(w.w, h.w, dx3);
            }
        }
    }
    __syncthreads();  // all GEMM reads of Wp done before aliasing as FW
    float* FW = Wp;   // FW[TE][FD]
    if (act) {
        const int c4 = 4 * cg;
        const float bb0 = b2[c4 + 0] + be2[c4 + 0];
        const float bb1 = b2[c4 + 1] + be2[c4 + 1];
        const float bb2 = b2[c4 + 2] + be2[c4 + 2];
        const float bb3 = b2[c4 + 3] + be2[c4 + 3];
        float4 o;
        o.x = ax0 + bb0; o.y = ax1 + bb1; o.z = ax2 + bb2; o.w = ax3 + bb3;
        *(float4*)&FW[(4 * rg + 0) * FD + c4] = o;
        o.x = bx0 + bb0; o.y = bx1 + bb1; o.z = bx2 + bb2; o.w = bx3 + bb3;
        *(float4*)&FW[(4 * rg + 1) * FD + c4] = o;
        o.x = cx0 + bb0; o.y = cx1 + bb1; o.z = cx2 + bb2; o.w = cx3 + bb3;
        *(float4*)&FW[(4 * rg + 2) * FD + c4] = o;
        o.x = dx0 + bb0; o.y = dx1 + bb1; o.z = dx2 + bb2; o.w = dx3 + bb3;
        *(float4*)&FW[(4 * rg + 3) * FD + c4] = o;
    }
    __syncthreads();

    if (PATH == 0) {
        // alpha_inv[e][H] = sum_j q[r]*k[s]*fw / sqrt(33)
        if (t < TE * 4) {
            int e = t >> 2, H = t & 3;
            float a = 0.0f;
            if (e0 + e < NE) {
                const float* qp = qt + rl[e] * FD + H * 33;
                const float* kp = kt + sl[e] * FD + H * 33;
                const float* fp = &FW[e * FD + H * 33];
                #pragma unroll
                for (int j = 0; j < 33; ++j)
                    a = fmaf(qp[j] * kp[j], fp[j], a);
                a *= 0.17407765595569785f;  // 1/sqrt(33)
            }
            al[t] = a;
        }
        __syncthreads();
        // scatter: d_inv[r] += cutoff * alpha[H] * v_inv[s]
        for (int idx = t; idx < TE * FD; idx += 256) {
            int e = idx / FD, j = idx - e * FD;
            if (e0 + e >= NE) continue;
            int H = j / 33;
            float v = cl[e] * al[e * 4 + H] * vt[sl[e] * FD + j];
            atomicAdd(&dout[rl[e] * FD + j], v);
        }
    } else {
        // alpha_ev[e][H] = sum_j q*k*fw / sqrt(44)
        if (t < TE * 3) {
            int e = t / 3, H = t - e * 3;
            float a = 0.0f;
            if (e0 + e < NE) {
                const float* qp = qt + rl[e] * FD + H * 44;
                const float* kp = kt + sl[e] * FD + H * 44;
                const float* fp = &FW[e * FD + H * 44];
                #pragma unroll
                for (int j = 0; j < 44; ++j)
                    a = fmaf(qp[j] * kp[j], fp[j], a);
                a *= 0.15075567228888181f;  // 1/sqrt(44)
            }
            al[e * 4 + H] = a;
        }
        __syncthreads();
        // scatter: d_ev[r][m] += cutoff * alpha[head(m)] * sh[e][m]
        for (int idx = t; idx < TE * EVD; idx += 256) {
            int e = idx / EVD, m = idx - e * EVD;
            if (e0 + e >= NE) continue;
            int hd = (m < 3) ? 0 : ((m < 8) ? 1 : 2);
            float v = cl[e] * al[e * 4 + hd] * sh[(e0 + e) * EVD + m];
            atomicAdd(&dout[rl[e] * EVD + m], v);
        }
    }
}

// ---------------- final node update ------------------------------------------
__global__ __launch_bounds__(256) void k_final(
    const float* __restrict__ xin, const float* __restrict__ evf,
    const float* __restrict__ dinv, const float* __restrict__ dev,
    const float* __restrict__ Wint, const float* __restrict__ bint,
    float* __restrict__ out)
{
    __shared__ float cat[8][136];  // att_inv(132) + evi2(3)
    __shared__ float aev[8][16];   // att_ev(15)
    __shared__ float tb[8][3];     // b_ev part of t
    const int t = threadIdx.x;
    const int n0 = blockIdx.x * 8;
    for (int idx = t; idx < 8 * FD; idx += 256) {
        int nl = idx / FD, j = idx - nl * FD;
        int n = n0 + nl;
        if (n < NN) cat[nl][j] = xin[n * FD + j] + dinv[n * FD + j];
    }
    for (int idx = t; idx < 8 * EVD; idx += 256) {
        int nl = idx / EVD, m = idx - nl * EVD;
        int n = n0 + nl;
        if (n < NN) aev[nl][m] = evf[n * EVD + m] + dev[n * EVD + m];
    }
    __syncthreads();
    if (t < 8 * 3) {
        int nl = t / 3, k = t - nl * 3;
        int lo = (k == 0) ? 0 : ((k == 1) ? 3 : 8);
        int hi = (k == 0) ? 3 : ((k == 1) ? 8 : 15);
        float s = 0.f;
        for (int m = lo; m < hi; ++m) { float v = aev[nl][m]; s = fmaf(v, v, s); }
        cat[nl][FD + k] = s;
    }
    __syncthreads();
    for (int idx = t; idx < 8 * 135; idx += 256) {
        int nl = idx / 135, j = idx - nl * 135;
        int n = n0 + nl;
        if (n >= NN) continue;
        float a = bint[j];
        #pragma unroll 5
        for (int c = 0; c < 135; ++c)
            a = fmaf(cat[nl][c], Wint[c * 135 + j], a);
        if (j < FD) out[n * FD + j] = cat[nl][j] + a;   // att_inv + d_inv2
        else        tb[nl][j - FD] = a;                 // b_ev
    }
    __syncthreads();
    for (int idx = t; idx < 8 * EVD; idx += 256) {
        int nl = idx / EVD, m = idx - nl * EVD;
        int n = n0 + nl;
        if (n >= NN) continue;
        int hd = (m < 3) ? 0 : ((m < 8) ? 1 : 2);
        out[NN * FD + n * EVD + m] = aev[nl][m] * (1.0f + tb[nl][hd]);
    }
}

extern "C" void kernel_launch(void* const* d_in, const int* in_sizes, int n_in,
                              void* d_out, int out_size, void* d_ws, size_t ws_size,
                              hipStream_t stream)
{
    (void)in_sizes; (void)n_in; (void)out_size; (void)ws_size;
    const float* xin  = (const float*)d_in[0];
    const float* evf  = (const float*)d_in[1];
    const float* rbf  = (const float*)d_in[2];
    const int*   snd  = (const int*)d_in[3];
    const int*   rcv  = (const int*)d_in[4];
    const float* sh   = (const float*)d_in[5];
    const float* cut  = (const float*)d_in[6];
    const float* Wq   = (const float*)d_in[7];
    const float* Wk   = (const float*)d_in[8];
    const float* Wv   = (const float*)d_in[9];
    const float* Wqe  = (const float*)d_in[10];
    const float* Wke  = (const float*)d_in[11];
    const float* Wint = (const float*)d_in[28];
    const float* bint = (const float*)d_in[29];

    float* ws   = (float*)d_ws;
    float* qinv = ws;                       // NN*FD
    float* kinv = qinv + NN * FD;
    float* vinv = kinv + NN * FD;
    float* qev  = vinv + NN * FD;
    float* kev  = qev  + NN * FD;
    float* evi  = kev  + NN * FD;           // NE*3
    float* dinv = evi  + NE * 3;            // NN*FD
    float* dev  = dinv + NN * FD;           // NN*EVD
    // total: 16.74M floats = 67 MB

    hipMemsetAsync(dinv, 0, (size_t)(NN * FD + NN * EVD) * sizeof(float), stream);

    k_proj<<<(NN + 7) / 8, 256, 0, stream>>>(xin, Wq, Wk, Wv, Wqe, Wke,
                                             qinv, kinv, vinv, qev, kev);
    k_evi<<<(NE + 255) / 256, 256, 0, stream>>>(evf, snd, rcv, evi);

    const int nt = (NE + TE - 1) / TE;
    k_edge<0><<<nt, 256, 0, stream>>>(rbf, evi, snd, rcv, cut, sh,
        (const float*)d_in[12], (const float*)d_in[13],
        (const float*)d_in[14], (const float*)d_in[15],
        (const float*)d_in[16], (const float*)d_in[17],
        (const float*)d_in[18], (const float*)d_in[19],
        qinv, kinv, vinv, dinv);
    k_edge<1><<<nt, 256, 0, stream>>>(rbf, evi, snd, rcv, cut, sh,
        (const float*)d_in[20], (const float*)d_in[21],
        (const float*)d_in[22], (const float*)d_in[23],
        (const float*)d_in[24], (const float*)d_in[25],
        (const float*)d_in[26], (const float*)d_in[27],
        qev, kev, nullptr, dev);

    k_final<<<(NN + 7) / 8, 256, 0, stream>>>(xin, evf, dinv, dev, Wint, bint,
                                              (float*)d_out);
}

// Round 3
// 939.757 us; speedup vs baseline: 1.0918x; 1.0918x over previous
//
#include <hip/hip_runtime.h>

// Euclidean transformer layer, MI355X fp32, round 3.
// N=20000 nodes, E=200000 edges, F=132, heads: inv 4x33, ev 3x44.
// Round-3 changes vs baseline: no W-staging in LDS (global reads, L1-resident),
// FW aliased onto HT (LDS 53KB -> ~24KB, 3 -> 6 blocks/CU), alpha phase
// parallelized across all 256 threads.

#define NN 20000
#define NE 200000
#define FD 132
#define RB 32
#define EVD 15
#define KTOT 165   // 132 h-rows + 33 g-rows
#define TE 28      // edges per block in k_edge

__device__ __forceinline__ float silu_f(float x) {
    return x / (1.0f + __expf(-x));
}

// ---------------- node projections: q/k/v_inv (4x33), q/k_ev (3x44) ----------
__global__ __launch_bounds__(256) void k_proj(
    const float* __restrict__ xin,
    const float* __restrict__ Wq, const float* __restrict__ Wk, const float* __restrict__ Wv,
    const float* __restrict__ Wqe, const float* __restrict__ Wke,
    float* __restrict__ qinv, float* __restrict__ kinv, float* __restrict__ vinv,
    float* __restrict__ qev, float* __restrict__ kev)
{
    __shared__ float xl[8][FD];
    const int t = threadIdx.x;
    const int n0 = blockIdx.x * 8;
    for (int idx = t; idx < 8 * FD; idx += 256) {
        int nl = idx / FD, j = idx - nl * FD;
        int n = n0 + nl;
        xl[nl][j] = (n < NN) ? xin[n * FD + j] : 0.0f;
    }
    __syncthreads();
    for (int idx = t; idx < 8 * FD; idx += 256) {
        int nl = idx / FD, j = idx - nl * FD;
        int n = n0 + nl;
        if (n >= NN) continue;
        {
            int H = j / 33, jj = j - H * 33;
            const float* xb = &xl[nl][H * 33];
            const float* wq = Wq + H * 1089 + jj;
            const float* wk = Wk + H * 1089 + jj;
            const float* wv = Wv + H * 1089 + jj;
            float aq = 0.f, ak = 0.f, av = 0.f;
            #pragma unroll
            for (int i = 0; i < 33; ++i) {
                float xv = xb[i];
                aq = fmaf(wq[i * 33], xv, aq);
                ak = fmaf(wk[i * 33], xv, ak);
                av = fmaf(wv[i * 33], xv, av);
            }
            qinv[n * FD + j] = aq; kinv[n * FD + j] = ak; vinv[n * FD + j] = av;
        }
        {
            int H = j / 44, jj = j - H * 44;
            const float* xb = &xl[nl][H * 44];
            const float* wq = Wqe + H * 1936 + jj;
            const float* wk = Wke + H * 1936 + jj;
            float aq = 0.f, ak = 0.f;
            #pragma unroll
            for (int i = 0; i < 44; ++i) {
                float xv = xb[i];
                aq = fmaf(wq[i * 44], xv, aq);
                ak = fmaf(wk[i * 44], xv, ak);
            }
            qev[n * FD + j] = aq; kev[n * FD + j] = ak;
        }
    }
}

// ---------------- per-edge SO(3) invariants of ev-diff ------------------------
__global__ __launch_bounds__(256) void k_evi(
    const float* __restrict__ ev, const int* __restrict__ snd,
    const int* __restrict__ rcv, float* __restrict__ evi)
{
    int e = blockIdx.x * 256 + threadIdx.x;
    if (e >= NE) return;
    int s = snd[e], r = rcv[e];
    const float* ps = &ev[s * EVD];
    const float* pr = &ev[r * EVD];
    float s0 = 0.f, s1 = 0.f, s2 = 0.f;
    #pragma unroll
    for (int m = 0; m < 3; ++m)  { float d = ps[m] - pr[m]; s0 = fmaf(d, d, s0); }
    #pragma unroll
    for (int m = 3; m < 8; ++m)  { float d = ps[m] - pr[m]; s1 = fmaf(d, d, s1); }
    #pragma unroll
    for (int m = 8; m < 15; ++m) { float d = ps[m] - pr[m]; s2 = fmaf(d, d, s2); }
    evi[e * 3 + 0] = s0; evi[e * 3 + 1] = s1; evi[e * 3 + 2] = s2;
}

// ---------------- fused edge kernel: filter GEMM + attention + scatter --------
// PATH 0: inv path (4 heads x 33, scatter 132/edge into d_inv)
// PATH 1: ev  path (3 heads x 44, scatter 15/edge into d_ev)
template<int PATH>
__global__ __launch_bounds__(256) void k_edge(
    const float* __restrict__ rbf, const float* __restrict__ evi,
    const int* __restrict__ snd, const int* __restrict__ rcv,
    const float* __restrict__ cut, const float* __restrict__ sh,
    const float* __restrict__ W1, const float* __restrict__ b1,
    const float* __restrict__ W2, const float* __restrict__ b2,
    const float* __restrict__ We1, const float* __restrict__ be1,
    const float* __restrict__ We2, const float* __restrict__ be2,
    const float* __restrict__ qt, const float* __restrict__ kt,
    const float* __restrict__ vt, float* __restrict__ dout)
{
    // HT[KTOT][TE] holds Hext during the GEMM; after the GEMM it is dead and
    // its first TE*FD floats are reused as FW[TE][FD] (then as the q*k*fw
    // product buffer, in place). 18.5 KB.
    __shared__ __align__(16) float HT[KTOT * TE];
    __shared__ float rbl[TE * RB];   // 3.5 KB
    __shared__ float evl[TE * 3];
    __shared__ int   sl[TE];
    __shared__ int   rl[TE];
    __shared__ float cl[TE];
    __shared__ float al[TE * 4];     // per-(edge,head) alpha * cutoff * scale

    const int t = threadIdx.x;
    const int e0 = blockIdx.x * TE;

    // ---- stage per-edge inputs ----
    for (int idx = t; idx < TE * RB; idx += 256) {
        int e = idx >> 5;
        rbl[idx] = (e0 + e < NE) ? rbf[e0 * RB + idx] : 0.0f;
    }
    for (int idx = t; idx < TE * 3; idx += 256) {
        int e = idx / 3;
        evl[idx] = (e0 + e < NE) ? evi[e0 * 3 + idx] : 0.0f;
    }
    if (t < TE) {
        int eg = e0 + t;
        sl[t] = (eg < NE) ? snd[eg] : 0;
        rl[t] = (eg < NE) ? rcv[eg] : 0;
        cl[t] = (eg < NE) ? cut[eg] : 0.0f;
    }
    __syncthreads();

    // ---- Hext rows 0..131: h = silu(rbf @ W1 + b1), layout HT[i][e] ----
    for (int idx = t; idx < TE * FD; idx += 256) {
        int e = idx / FD, i = idx - e * FD;
        float v = 0.0f;
        if (e0 + e < NE) {
            float a = b1[i];
            #pragma unroll
            for (int k = 0; k < RB; ++k)
                a = fmaf(rbl[e * RB + k], W1[k * FD + i], a);
            v = silu_f(a);
        }
        HT[i * TE + e] = v;
    }
    // ---- Hext rows 132..164: g = silu(evi @ We1 + be1) ----
    for (int idx = t; idx < TE * 33; idx += 256) {
        int e = idx / 33, ii = idx - e * 33;
        float v = 0.0f;
        if (e0 + e < NE) {
            float a = be1[ii];
            a = fmaf(evl[e * 3 + 0], We1[ii], a);
            a = fmaf(evl[e * 3 + 1], We1[33 + ii], a);
            a = fmaf(evl[e * 3 + 2], We1[66 + ii], a);
            v = silu_f(a);
        }
        HT[(FD + ii) * TE + e] = v;
    }
    __syncthreads();

    // ---- main GEMM: fw[TE][132] = Hext[TE][165] @ Wcat[165][132] ----
    // thread (cg,rg): cols 4cg..4cg+3, edges 4rg..4rg+3 (231 active threads).
    // W read straight from global: per wave one contiguous 528B row segment,
    // L1-resident across waves (87KB unique per block).
    const int cg = t % 33;
    const int rg = t / 33;
    const bool act = (t < 231);
    float ax0=0,ax1=0,ax2=0,ax3=0;
    float bx0=0,bx1=0,bx2=0,bx3=0;
    float cx0=0,cx1=0,cx2=0,cx3=0;
    float dx0=0,dx1=0,dx2=0,dx3=0;
    if (act) {
        const float* wbase  = W2  + 4 * cg;
        const float* webase = We2 + 4 * cg;
        const float* hbase  = HT  + 4 * rg;
        #pragma unroll 4
        for (int i = 0; i < FD; ++i) {
            const float4 w = *(const float4*)(wbase + i * FD);
            const float4 h = *(const float4*)(hbase + i * TE);
            ax0 = fmaf(w.x, h.x, ax0); ax1 = fmaf(w.y, h.x, ax1);
            ax2 = fmaf(w.z, h.x, ax2); ax3 = fmaf(w.w, h.x, ax3);
            bx0 = fmaf(w.x, h.y, bx0); bx1 = fmaf(w.y, h.y, bx1);
            bx2 = fmaf(w.z, h.y, bx2); bx3 = fmaf(w.w, h.y, bx3);
            cx0 = fmaf(w.x, h.z, cx0); cx1 = fmaf(w.y, h.z, cx1);
            cx2 = fmaf(w.z, h.z, cx2); cx3 = fmaf(w.w, h.z, cx3);
            dx0 = fmaf(w.x, h.w, dx0); dx1 = fmaf(w.y, h.w, dx1);
            dx2 = fmaf(w.z, h.w, dx2); dx3 = fmaf(w.w, h.w, dx3);
        }
        #pragma unroll 4
        for (int i = 0; i < 33; ++i) {
            const float4 w = *(const float4*)(webase + i * FD);
            const float4 h = *(const float4*)(hbase + (FD + i) * TE);
            ax0 = fmaf(w.x, h.x, ax0); ax1 = fmaf(w.y, h.x, ax1);
            ax2 = fmaf(w.z, h.x, ax2); ax3 = fmaf(w.w, h.x, ax3);
            bx0 = fmaf(w.x, h.y, bx0); bx1 = fmaf(w.y, h.y, bx1);
            bx2 = fmaf(w.z, h.y, bx2); bx3 = fmaf(w.w, h.y, bx3);
            cx0 = fmaf(w.x, h.z, cx0); cx1 = fmaf(w.y, h.z, cx1);
            cx2 = fmaf(w.z, h.z, cx2); cx3 = fmaf(w.w, h.z, cx3);
            dx0 = fmaf(w.x, h.w, dx0); dx1 = fmaf(w.y, h.w, dx1);
            dx2 = fmaf(w.z, h.w, dx2); dx3 = fmaf(w.w, h.w, dx3);
        }
    }
    __syncthreads();  // all HT reads done; safe to alias as FW
    float* FW = HT;   // FW[TE][FD]
    if (act) {
        const int c4 = 4 * cg;
        const float bb0 = b2[c4 + 0] + be2[c4 + 0];
        const float bb1 = b2[c4 + 1] + be2[c4 + 1];
        const float bb2 = b2[c4 + 2] + be2[c4 + 2];
        const float bb3 = b2[c4 + 3] + be2[c4 + 3];
        float4 o;
        o.x = ax0 + bb0; o.y = ax1 + bb1; o.z = ax2 + bb2; o.w = ax3 + bb3;
        *(float4*)&FW[(4 * rg + 0) * FD + c4] = o;
        o.x = bx0 + bb0; o.y = bx1 + bb1; o.z = bx2 + bb2; o.w = bx3 + bb3;
        *(float4*)&FW[(4 * rg + 1) * FD + c4] = o;
        o.x = cx0 + bb0; o.y = cx1 + bb1; o.z = cx2 + bb2; o.w = cx3 + bb3;
        *(float4*)&FW[(4 * rg + 2) * FD + c4] = o;
        o.x = dx0 + bb0; o.y = dx1 + bb1; o.z = dx2 + bb2; o.w = dx3 + bb3;
        *(float4*)&FW[(4 * rg + 3) * FD + c4] = o;
    }
    __syncthreads();

    // ---- alpha products, parallel over all threads: FW[e][j] *= q*k ----
    // (coalesced row gathers of q[rcv[e]] and k[snd[e]]; in-place in LDS)
    for (int idx = t; idx < TE * FD; idx += 256) {
        int e = idx / FD, j = idx - e * FD;
        float qk = qt[rl[e] * FD + j] * kt[sl[e] * FD + j];
        FW[idx] *= qk;
    }
    __syncthreads();

    // ---- per-(edge,head) segment sums; cutoff & 1/sqrt(D) folded in ----
    if (PATH == 0) {
        if (t < TE * 4) {
            int e = t >> 2, H = t & 3;
            const float* fp = &FW[e * FD + H * 33];
            float a = 0.0f;
            #pragma unroll
            for (int j = 0; j < 33; ++j) a += fp[j];
            al[t] = a * cl[e] * 0.17407765595569785f;  // cutoff / sqrt(33)
        }
    } else {
        if (t < TE * 3) {
            int e = t / 3, H = t - e * 3;
            const float* fp = &FW[e * FD + H * 44];
            float a = 0.0f;
            #pragma unroll
            for (int j = 0; j < 44; ++j) a += fp[j];
            al[e * 4 + H] = a * cl[e] * 0.15075567228888181f;  // cutoff / sqrt(44)
        }
    }
    __syncthreads();

    // ---- scatter ----
    if (PATH == 0) {
        for (int idx = t; idx < TE * FD; idx += 256) {
            int e = idx / FD, j = idx - e * FD;
            if (e0 + e >= NE) continue;
            int H = j / 33;
            float v = al[e * 4 + H] * vt[sl[e] * FD + j];
            atomicAdd(&dout[rl[e] * FD + j], v);
        }
    } else {
        for (int idx = t; idx < TE * EVD; idx += 256) {
            int e = idx / EVD, m = idx - e * EVD;
            if (e0 + e >= NE) continue;
            int hd = (m < 3) ? 0 : ((m < 8) ? 1 : 2);
            float v = al[e * 4 + hd] * sh[(e0 + e) * EVD + m];
            atomicAdd(&dout[rl[e] * EVD + m], v);
        }
    }
}

// ---------------- final node update ------------------------------------------
__global__ __launch_bounds__(256) void k_final(
    const float* __restrict__ xin, const float* __restrict__ evf,
    const float* __restrict__ dinv, const float* __restrict__ dev,
    const float* __restrict__ Wint, const float* __restrict__ bint,
    float* __restrict__ out)
{
    __shared__ float cat[8][136];  // att_inv(132) + evi2(3)
    __shared__ float aev[8][16];   // att_ev(15)
    __shared__ float tb[8][3];     // b_ev part of t
    const int t = threadIdx.x;
    const int n0 = blockIdx.x * 8;
    for (int idx = t; idx < 8 * FD; idx += 256) {
        int nl = idx / FD, j = idx - nl * FD;
        int n = n0 + nl;
        if (n < NN) cat[nl][j] = xin[n * FD + j] + dinv[n * FD + j];
    }
    for (int idx = t; idx < 8 * EVD; idx += 256) {
        int nl = idx / EVD, m = idx - nl * EVD;
        int n = n0 + nl;
        if (n < NN) aev[nl][m] = evf[n * EVD + m] + dev[n * EVD + m];
    }
    __syncthreads();
    if (t < 8 * 3) {
        int nl = t / 3, k = t - nl * 3;
        int lo = (k == 0) ? 0 : ((k == 1) ? 3 : 8);
        int hi = (k == 0) ? 3 : ((k == 1) ? 8 : 15);
        float s = 0.f;
        for (int m = lo; m < hi; ++m) { float v = aev[nl][m]; s = fmaf(v, v, s); }
        cat[nl][FD + k] = s;
    }
    __syncthreads();
    for (int idx = t; idx < 8 * 135; idx += 256) {
        int nl = idx / 135, j = idx - nl * 135;
        int n = n0 + nl;
        if (n >= NN) continue;
        float a = bint[j];
        #pragma unroll 5
        for (int c = 0; c < 135; ++c)
            a = fmaf(cat[nl][c], Wint[c * 135 + j], a);
        if (j < FD) out[n * FD + j] = cat[nl][j] + a;   // att_inv + d_inv2
        else        tb[nl][j - FD] = a;                 // b_ev
    }
    __syncthreads();
    for (int idx = t; idx < 8 * EVD; idx += 256) {
        int nl = idx / EVD, m = idx - nl * EVD;
        int n = n0 + nl;
        if (n >= NN) continue;
        int hd = (m < 3) ? 0 : ((m < 8) ? 1 : 2);
        out[NN * FD + n * EVD + m] = aev[nl][m] * (1.0f + tb[nl][hd]);
    }
}

extern "C" void kernel_launch(void* const* d_in, const int* in_sizes, int n_in,
                              void* d_out, int out_size, void* d_ws, size_t ws_size,
                              hipStream_t stream)
{
    (void)in_sizes; (void)n_in; (void)out_size; (void)ws_size;
    const float* xin  = (const float*)d_in[0];
    const float* evf  = (const float*)d_in[1];
    const float* rbf  = (const float*)d_in[2];
    const int*   snd  = (const int*)d_in[3];
    const int*   rcv  = (const int*)d_in[4];
    const float* sh   = (const float*)d_in[5];
    const float* cut  = (const float*)d_in[6];
    const float* Wq   = (const float*)d_in[7];
    const float* Wk   = (const float*)d_in[8];
    const float* Wv   = (const float*)d_in[9];
    const float* Wqe  = (const float*)d_in[10];
    const float* Wke  = (const float*)d_in[11];
    const float* Wint = (const float*)d_in[28];
    const float* bint = (const float*)d_in[29];

    float* ws   = (float*)d_ws;
    float* qinv = ws;                       // NN*FD
    float* kinv = qinv + NN * FD;
    float* vinv = kinv + NN * FD;
    float* qev  = vinv + NN * FD;
    float* kev  = qev  + NN * FD;
    float* evi  = kev  + NN * FD;           // NE*3
    float* dinv = evi  + NE * 3;            // NN*FD
    float* dev  = dinv + NN * FD;           // NN*EVD

    hipMemsetAsync(dinv, 0, (size_t)(NN * FD + NN * EVD) * sizeof(float), stream);

    k_proj<<<(NN + 7) / 8, 256, 0, stream>>>(xin, Wq, Wk, Wv, Wqe, Wke,
                                             qinv, kinv, vinv, qev, kev);
    k_evi<<<(NE + 255) / 256, 256, 0, stream>>>(evf, snd, rcv, evi);

    const int nt = (NE + TE - 1) / TE;
    k_edge<0><<<nt, 256, 0, stream>>>(rbf, evi, snd, rcv, cut, sh,
        (const float*)d_in[12], (const float*)d_in[13],
        (const float*)d_in[14], (const float*)d_in[15],
        (const float*)d_in[16], (const float*)d_in[17],
        (const float*)d_in[18], (const float*)d_in[19],
        qinv, kinv, vinv, dinv);
    k_edge<1><<<nt, 256, 0, stream>>>(rbf, evi, snd, rcv, cut, sh,
        (const float*)d_in[20], (const float*)d_in[21],
        (const float*)d_in[22], (const float*)d_in[23],
        (const float*)d_in[24], (const float*)d_in[25],
        (const float*)d_in[26], (const float*)d_in[27],
        qev, kev, nullptr, dev);

    k_final<<<(NN + 7) / 8, 256, 0, stream>>>(xin, evf, dinv, dev, Wint, bint,
                                              (float*)d_out);
}

// Round 6
// 923.512 us; speedup vs baseline: 1.1110x; 1.0176x over previous
//
#include <hip/hip_runtime.h>

// Euclidean transformer layer, MI355X, round 4: bf16 MFMA filter GEMMs.
// N=20000 nodes, E=200000 edges, F=132, heads: inv 4x33, ev 3x44.

#define NN 20000
#define NE 200000
#define FD 132
#define RB 32
#define EVD 15
#define TE 64      // edges per block (200000 = 3125 * 64, exact)
#define KPAD 200   // HT LDS k-stride in bf16 (400B rows -> 2-way banks only)
#define KG 192     // global W2T k-stride (165 rounded up to mult of 32)
#define NP 144     // padded n (132 -> 9 tiles of 16)

typedef __attribute__((ext_vector_type(8))) short bf16x8;
typedef __attribute__((ext_vector_type(4))) float f32x4;

__device__ __forceinline__ float silu_f(float x) {
    return x / (1.0f + __expf(-x));
}
__device__ __forceinline__ unsigned short f2bf(float x) {
    union { float f; unsigned u; } v; v.f = x;
    unsigned r = v.u + 0x7FFF + ((v.u >> 16) & 1);   // RNE
    return (unsigned short)(r >> 16);
}

// ---------------- prep: transpose/convert weights (idempotent, every call) ---
__global__ __launch_bounds__(256) void k_prep(
    const float* __restrict__ Wq, const float* __restrict__ Wk, const float* __restrict__ Wv,
    const float* __restrict__ Wqe, const float* __restrict__ Wke,
    const float* __restrict__ fiW1, const float* __restrict__ fiW2, const float* __restrict__ fiWe2,
    const float* __restrict__ feW1, const float* __restrict__ feW2, const float* __restrict__ feWe2,
    unsigned short* __restrict__ W1Tfi, unsigned short* __restrict__ W1Tfe,
    unsigned short* __restrict__ W2Tfi, unsigned short* __restrict__ W2Tfe,
    float* __restrict__ WqT, float* __restrict__ WkT, float* __restrict__ WvT,
    float* __restrict__ WqeT, float* __restrict__ WkeT)
{
    const int gid = blockIdx.x * 256 + threadIdx.x;
    const int gs  = gridDim.x * 256;
    // W1T[n][k] (bf16, [144][32])
    for (int idx = gid; idx < NP * RB; idx += gs) {
        int n = idx / RB, k = idx - n * RB;
        W1Tfi[idx] = f2bf((n < FD) ? fiW1[k * FD + n] : 0.0f);
        W1Tfe[idx] = f2bf((n < FD) ? feW1[k * FD + n] : 0.0f);
    }
    // W2T[n][k] (bf16, [144][192]): k<132 from W2, 132<=k<165 from We2, else 0
    for (int idx = gid; idx < NP * KG; idx += gs) {
        int n = idx / KG, k = idx - n * KG;
        float vi = 0.0f, ve = 0.0f;
        if (n < FD) {
            if (k < FD)       { vi = fiW2[k * FD + n];          ve = feW2[k * FD + n]; }
            else if (k < 165) { vi = fiWe2[(k - FD) * FD + n];  ve = feWe2[(k - FD) * FD + n]; }
        }
        W2Tfi[idx] = f2bf(vi);
        W2Tfe[idx] = f2bf(ve);
    }
    // WqT/WkT/WvT [4][33][36] fp32: WT[H][j][i] = W[H][i][j], i-pad 0
    for (int idx = gid; idx < 4 * 33 * 36; idx += gs) {
        int H = idx / (33 * 36), rem = idx - H * (33 * 36);
        int j = rem / 36, i = rem - j * 36;
        float q = 0.f, k = 0.f, v = 0.f;
        if (i < 33) {
            q = Wq[H * 1089 + i * 33 + j];
            k = Wk[H * 1089 + i * 33 + j];
            v = Wv[H * 1089 + i * 33 + j];
        }
        WqT[idx] = q; WkT[idx] = k; WvT[idx] = v;
    }
    // WqeT/WkeT [3][44][44] fp32
    for (int idx = gid; idx < 3 * 44 * 44; idx += gs) {
        int H = idx / 1936, rem = idx - H * 1936;
        int j = rem / 44, i = rem - j * 44;
        WqeT[idx] = Wqe[H * 1936 + i * 44 + j];
        WkeT[idx] = Wke[H * 1936 + i * 44 + j];
    }
}

// ---------------- node projections (transposed weights, float4 reads) --------
__global__ __launch_bounds__(256) void k_proj(
    const float* __restrict__ xin,
    const float* __restrict__ WqT, const float* __restrict__ WkT, const float* __restrict__ WvT,
    const float* __restrict__ WqeT, const float* __restrict__ WkeT,
    float* __restrict__ qinv, float* __restrict__ kinv, float* __restrict__ vinv,
    float* __restrict__ qev, float* __restrict__ kev)
{
    __shared__ float xl[8][136];
    const int t = threadIdx.x;
    const int n0 = blockIdx.x * 8;
    for (int idx = t; idx < 8 * 136; idx += 256) {
        int nl = idx / 136, j = idx - nl * 136;
        int n = n0 + nl;
        xl[nl][j] = (j < FD && n < NN) ? xin[n * FD + j] : 0.0f;
    }
    __syncthreads();
    for (int idx = t; idx < 8 * FD; idx += 256) {
        int nl = idx / FD, j = idx - nl * FD;
        int n = n0 + nl;
        if (n >= NN) continue;
        {
            int H = j / 33, jj = j - H * 33;
            const float* xb = &xl[nl][H * 33];
            const float* wq = WqT + (H * 33 + jj) * 36;
            const float* wk = WkT + (H * 33 + jj) * 36;
            const float* wv = WvT + (H * 33 + jj) * 36;
            float aq = 0.f, ak = 0.f, av = 0.f;
            #pragma unroll
            for (int i4 = 0; i4 < 9; ++i4) {
                const float4 q4 = *(const float4*)(wq + i4 * 4);
                const float4 k4 = *(const float4*)(wk + i4 * 4);
                const float4 v4 = *(const float4*)(wv + i4 * 4);
                float x0 = xb[i4 * 4 + 0], x1 = xb[i4 * 4 + 1];
                float x2 = xb[i4 * 4 + 2], x3 = xb[i4 * 4 + 3];
                aq = fmaf(q4.x, x0, aq); aq = fmaf(q4.y, x1, aq);
                aq = fmaf(q4.z, x2, aq); aq = fmaf(q4.w, x3, aq);
                ak = fmaf(k4.x, x0, ak); ak = fmaf(k4.y, x1, ak);
                ak = fmaf(k4.z, x2, ak); ak = fmaf(k4.w, x3, ak);
                av = fmaf(v4.x, x0, av); av = fmaf(v4.y, x1, av);
                av = fmaf(v4.z, x2, av); av = fmaf(v4.w, x3, av);
            }
            qinv[n * FD + j] = aq; kinv[n * FD + j] = ak; vinv[n * FD + j] = av;
        }
        {
            int H = j / 44, jj = j - H * 44;
            const float* xb = &xl[nl][H * 44];
            const float* wq = WqeT + (H * 44 + jj) * 44;
            const float* wk = WkeT + (H * 44 + jj) * 44;
            float aq = 0.f, ak = 0.f;
            #pragma unroll
            for (int i4 = 0; i4 < 11; ++i4) {
                const float4 q4 = *(const float4*)(wq + i4 * 4);
                const float4 k4 = *(const float4*)(wk + i4 * 4);
                float x0 = xb[i4 * 4 + 0], x1 = xb[i4 * 4 + 1];
                float x2 = xb[i4 * 4 + 2], x3 = xb[i4 * 4 + 3];
                aq = fmaf(q4.x, x0, aq); aq = fmaf(q4.y, x1, aq);
                aq = fmaf(q4.z, x2, aq); aq = fmaf(q4.w, x3, aq);
                ak = fmaf(k4.x, x0, ak); ak = fmaf(k4.y, x1, ak);
                ak = fmaf(k4.z, x2, ak); ak = fmaf(k4.w, x3, ak);
            }
            qev[n * FD + j] = aq; kev[n * FD + j] = ak;
        }
    }
}

// ---------------- per-edge SO(3) invariants of ev-diff ------------------------
__global__ __launch_bounds__(256) void k_evi(
    const float* __restrict__ ev, const int* __restrict__ snd,
    const int* __restrict__ rcv, float* __restrict__ evi)
{
    int e = blockIdx.x * 256 + threadIdx.x;
    if (e >= NE) return;
    int s = snd[e], r = rcv[e];
    const float* ps = &ev[s * EVD];
    const float* pr = &ev[r * EVD];
    float s0 = 0.f, s1 = 0.f, s2 = 0.f;
    #pragma unroll
    for (int m = 0; m < 3; ++m)  { float d = ps[m] - pr[m]; s0 = fmaf(d, d, s0); }
    #pragma unroll
    for (int m = 3; m < 8; ++m)  { float d = ps[m] - pr[m]; s1 = fmaf(d, d, s1); }
    #pragma unroll
    for (int m = 8; m < 15; ++m) { float d = ps[m] - pr[m]; s2 = fmaf(d, d, s2); }
    evi[e * 3 + 0] = s0; evi[e * 3 + 1] = s1; evi[e * 3 + 2] = s2;
}

// ---------------- fused edge kernel: MFMA filter + attention + scatter --------
template<int PATH>
__global__ __launch_bounds__(256, 4) void k_edge(
    const float* __restrict__ rbf, const float* __restrict__ evi,
    const int* __restrict__ snd, const int* __restrict__ rcv,
    const float* __restrict__ cut, const float* __restrict__ sh,
    const unsigned short* __restrict__ W1T,  // [144][32] bf16
    const float* __restrict__ b1,
    const unsigned short* __restrict__ W2T,  // [144][192] bf16
    const float* __restrict__ b2,
    const float* __restrict__ We1, const float* __restrict__ be1,
    const float* __restrict__ be2,
    const float* __restrict__ qt, const float* __restrict__ kt,
    const float* __restrict__ vt, float* __restrict__ dout)
{
    // lds_buf: first holds HT [64][200] bf16 (25.6KB), then aliased FW [64][132] f32 (33.8KB)
    __shared__ __align__(16) char lds_buf[TE * FD * 4];
    __shared__ float evl[TE * 3];
    __shared__ int   sl[TE];
    __shared__ int   rl[TE];
    __shared__ float cl[TE];
    __shared__ float al[TE * 4];

    typedef unsigned short (*HTp)[KPAD];
    HTp HT   = (HTp)lds_buf;
    float* FW = (float*)lds_buf;

    const int t    = threadIdx.x;
    const int wv   = t >> 6;
    const int ln   = t & 63;
    const int lrow = ln & 15;    // A-row / B-col / D-col within tile
    const int kseg = ln >> 4;    // 0..3
    const int e0   = blockIdx.x * TE;

    if (t < TE) {
        sl[t] = snd[e0 + t];
        rl[t] = rcv[e0 + t];
        cl[t] = cut[e0 + t];
    }
    for (int idx = t; idx < TE * 3; idx += 256) evl[idx] = evi[e0 * 3 + idx];
    __syncthreads();

    // ---- H-GEMM: h = silu(rbf @ W1 + b1), one K=32 MFMA per n-tile ----
    {
        const int erow = e0 + 16 * wv + lrow;
        const float4 ra = *(const float4*)&rbf[erow * RB + kseg * 8];
        const float4 rb = *(const float4*)&rbf[erow * RB + kseg * 8 + 4];
        bf16x8 afrag;
        afrag[0] = (short)f2bf(ra.x); afrag[1] = (short)f2bf(ra.y);
        afrag[2] = (short)f2bf(ra.z); afrag[3] = (short)f2bf(ra.w);
        afrag[4] = (short)f2bf(rb.x); afrag[5] = (short)f2bf(rb.y);
        afrag[6] = (short)f2bf(rb.z); afrag[7] = (short)f2bf(rb.w);
        #pragma unroll
        for (int nt = 0; nt < 9; ++nt) {
            const int ncol = nt * 16 + lrow;
            bf16x8 bfrag = *(const bf16x8*)&W1T[ncol * RB + kseg * 8];
            f32x4 acc = {0.f, 0.f, 0.f, 0.f};
            acc = __builtin_amdgcn_mfma_f32_16x16x32_bf16(afrag, bfrag, acc, 0, 0, 0);
            if (ncol < FD) {
                const float bias = b1[ncol];
                #pragma unroll
                for (int r = 0; r < 4; ++r)
                    HT[16 * wv + kseg * 4 + r][ncol] = f2bf(silu_f(acc[r] + bias));
            }
        }
    }
    // g rows 132..164: silu(evi @ We1 + be1)
    for (int idx = t; idx < TE * 33; idx += 256) {
        int e = idx / 33, ii = idx - e * 33;
        float a = be1[ii];
        a = fmaf(evl[e * 3 + 0], We1[ii], a);
        a = fmaf(evl[e * 3 + 1], We1[33 + ii], a);
        a = fmaf(evl[e * 3 + 2], We1[66 + ii], a);
        HT[e][FD + ii] = f2bf(silu_f(a));
    }
    // zero-pad k 165..199
    for (int idx = t; idx < TE * (KPAD - 165); idx += 256) {
        int e = idx / (KPAD - 165), kk = idx - e * (KPAD - 165);
        HT[e][165 + kk] = 0;
    }
    __syncthreads();

    // ---- main GEMM: fw[64][132] = Hext[64][165] @ Wcat[165][132], bf16 MFMA ----
    f32x4 acc[9];
    #pragma unroll
    for (int nt = 0; nt < 9; ++nt) acc[nt] = (f32x4){0.f, 0.f, 0.f, 0.f};
    {
        const unsigned short* hrow = &HT[16 * wv + lrow][0];
        #pragma unroll
        for (int kt = 0; kt < 6; ++kt) {
            bf16x8 afrag = *(const bf16x8*)&hrow[kt * 32 + kseg * 8];
            #pragma unroll
            for (int nt = 0; nt < 9; ++nt) {
                bf16x8 bfrag = *(const bf16x8*)&W2T[(nt * 16 + lrow) * KG + kt * 32 + kseg * 8];
                acc[nt] = __builtin_amdgcn_mfma_f32_16x16x32_bf16(afrag, bfrag, acc[nt], 0, 0, 0);
            }
        }
    }
    __syncthreads();   // HT dead; safe to overwrite as FW

    #pragma unroll
    for (int nt = 0; nt < 9; ++nt) {
        const int ncol = nt * 16 + lrow;
        if (ncol < FD) {
            const float bias = b2[ncol] + be2[ncol];
            #pragma unroll
            for (int r = 0; r < 4; ++r)
                FW[(16 * wv + kseg * 4 + r) * FD + ncol] = acc[nt][r] + bias;
        }
    }
    __syncthreads();

    // ---- qk products in place: FW[e][j] *= q[rcv][j] * k[snd][j] ----
    for (int idx = t; idx < TE * FD; idx += 256) {
        int e = idx / FD, j = idx - e * FD;
        FW[idx] *= qt[rl[e] * FD + j] * kt[sl[e] * FD + j];
    }
    __syncthreads();

    // ---- per-(edge,head) sums; cutoff & 1/sqrt(D) folded in ----
    if (PATH == 0) {
        {   // 256 threads = 64 edges x 4 heads, exact
            int e = t >> 2, H = t & 3;
            const float* fp = &FW[e * FD + H * 33];
            float a = 0.0f;
            #pragma unroll
            for (int j = 0; j < 33; ++j) a += fp[j];
            al[t] = a * cl[e] * 0.17407765595569785f;  // cutoff / sqrt(33)
        }
    } else {
        if (t < TE * 3) {
            int e = t / 3, H = t - e * 3;
            const float* fp = &FW[e * FD + H * 44];
            float a = 0.0f;
            #pragma unroll
            for (int j = 0; j < 44; ++j) a += fp[j];
            al[e * 4 + H] = a * cl[e] * 0.15075567228888181f;  // cutoff / sqrt(44)
        }
    }
    __syncthreads();

    // ---- scatter ----
    if (PATH == 0) {
        for (int idx = t; idx < TE * FD; idx += 256) {
            int e = idx / FD, j = idx - e * FD;
            float v = al[e * 4 + j / 33] * vt[sl[e] * FD + j];
            atomicAdd(&dout[rl[e] * FD + j], v);
        }
    } else {
        for (int idx = t; idx < TE * EVD; idx += 256) {
            int e = idx / EVD, m = idx - e * EVD;
            int hd = (m < 3) ? 0 : ((m < 8) ? 1 : 2);
            float v = al[e * 4 + hd] * sh[(e0 + e) * EVD + m];
            atomicAdd(&dout[rl[e] * EVD + m], v);
        }
    }
}

// ---------------- final node update ------------------------------------------
__global__ __launch_bounds__(256) void k_final(
    const float* __restrict__ xin, const float* __restrict__ evf,
    const float* __restrict__ dinv, const float* __restrict__ dev,
    const float* __restrict__ Wint, const float* __restrict__ bint,
    float* __restrict__ out)
{
    __shared__ float cat[8][136];
    __shared__ float aev[8][16];
    __shared__ float tb[8][3];
    const int t = threadIdx.x;
    const int n0 = blockIdx.x * 8;
    for (int idx = t; idx < 8 * FD; idx += 256) {
        int nl = idx / FD, j = idx - nl * FD;
        int n = n0 + nl;
        if (n < NN) cat[nl][j] = xin[n * FD + j] + dinv[n * FD + j];
    }
    for (int idx = t; idx < 8 * EVD; idx += 256) {
        int nl = idx / EVD, m = idx - nl * EVD;
        int n = n0 + nl;
        if (n < NN) aev[nl][m] = evf[n * EVD + m] + dev[n * EVD + m];
    }
    __syncthreads();
    if (t < 8 * 3) {
        int nl = t / 3, k = t - nl * 3;
        int lo = (k == 0) ? 0 : ((k == 1) ? 3 : 8);
        int hi = (k == 0) ? 3 : ((k == 1) ? 8 : 15);
        float s = 0.f;
        for (int m = lo; m < hi; ++m) { float v = aev[nl][m]; s = fmaf(v, v, s); }
        cat[nl][FD + k] = s;
    }
    __syncthreads();
    for (int idx = t; idx < 8 * 135; idx += 256) {
        int nl = idx / 135, j = idx - nl * 135;
        int n = n0 + nl;
        if (n >= NN) continue;
        float a = bint[j];
        #pragma unroll 5
        for (int c = 0; c < 135; ++c)
            a = fmaf(cat[nl][c], Wint[c * 135 + j], a);
        if (j < FD) out[n * FD + j] = cat[nl][j] + a;
        else        tb[nl][j - FD] = a;
    }
    __syncthreads();
    for (int idx = t; idx < 8 * EVD; idx += 256) {
        int nl = idx / EVD, m = idx - nl * EVD;
        int n = n0 + nl;
        if (n >= NN) continue;
        int hd = (m < 3) ? 0 : ((m < 8) ? 1 : 2);
        out[NN * FD + n * EVD + m] = aev[nl][m] * (1.0f + tb[nl][hd]);
    }
}

extern "C" void kernel_launch(void* const* d_in, const int* in_sizes, int n_in,
                              void* d_out, int out_size, void* d_ws, size_t ws_size,
                              hipStream_t stream)
{
    (void)in_sizes; (void)n_in; (void)out_size; (void)ws_size;
    const float* xin  = (const float*)d_in[0];
    const float* evf  = (const float*)d_in[1];
    const float* rbf  = (const float*)d_in[2];
    const int*   snd  = (const int*)d_in[3];
    const int*   rcv  = (const int*)d_in[4];
    const float* sh   = (const float*)d_in[5];
    const float* cut  = (const float*)d_in[6];
    const float* Wint = (const float*)d_in[28];
    const float* bint = (const float*)d_in[29];

    float* ws   = (float*)d_ws;
    float* qinv = ws;                       // NN*FD
    float* kinv = qinv + NN * FD;
    float* vinv = kinv + NN * FD;
    float* qev  = vinv + NN * FD;
    float* kev  = qev  + NN * FD;
    float* evi  = kev  + NN * FD;           // NE*3
    float* dinv = evi  + NE * 3;            // NN*FD
    float* dev  = dinv + NN * FD;           // NN*EVD
    float* wtail = dev + NN * EVD;          // prep region (16B-aligned)

    unsigned short* W2Tfi = (unsigned short*)wtail;        // 27648 bf16
    unsigned short* W2Tfe = W2Tfi + NP * KG;               // 27648
    unsigned short* W1Tfi = W2Tfe + NP * KG;               // 4608
    unsigned short* W1Tfe = W1Tfi + NP * RB;               // 4608
    float* WqT  = (float*)(W1Tfe + NP * RB);               // 4752 f32
    float* WkT  = WqT  + 4 * 33 * 36;
    float* WvT  = WkT  + 4 * 33 * 36;
    float* WqeT = WvT  + 4 * 33 * 36;                      // 5808 f32
    float* WkeT = WqeT + 3 * 44 * 44;

    hipMemsetAsync(dinv, 0, (size_t)(NN * FD + NN * EVD) * sizeof(float), stream);

    k_prep<<<64, 256, 0, stream>>>(
        (const float*)d_in[7], (const float*)d_in[8], (const float*)d_in[9],
        (const float*)d_in[10], (const float*)d_in[11],
        (const float*)d_in[12], (const float*)d_in[14], (const float*)d_in[18],
        (const float*)d_in[20], (const float*)d_in[22], (const float*)d_in[26],
        W1Tfi, W1Tfe, W2Tfi, W2Tfe, WqT, WkT, WvT, WqeT, WkeT);

    k_proj<<<(NN + 7) / 8, 256, 0, stream>>>(xin, WqT, WkT, WvT, WqeT, WkeT,
                                             qinv, kinv, vinv, qev, kev);
    k_evi<<<(NE + 255) / 256, 256, 0, stream>>>(evf, snd, rcv, evi);

    const int nt = NE / TE;  // 3125, exact
    k_edge<0><<<nt, 256, 0, stream>>>(rbf, evi, snd, rcv, cut, sh,
        W1Tfi, (const float*)d_in[13], W2Tfi, (const float*)d_in[15],
        (const float*)d_in[16], (const float*)d_in[17], (const float*)d_in[19],
        qinv, kinv, vinv, dinv);
    k_edge<1><<<nt, 256, 0, stream>>>(rbf, evi, snd, rcv, cut, sh,
        W1Tfe, (const float*)d_in[21], W2Tfe, (const float*)d_in[23],
        (const float*)d_in[24], (const float*)d_in[25], (const float*)d_in[27],
        qev, kev, nullptr, dev);

    k_final<<<(NN + 7) / 8, 256, 0, stream>>>(xin, evf, dinv, dev, Wint, bint,
                                              (float*)d_out);
}

// Round 7
// 668.857 us; speedup vs baseline: 1.5340x; 1.3807x over previous
//
#include <hip/hip_runtime.h>

// Euclidean transformer layer, MI355X, round 7.
// k_edge: bf16 MFMA filter GEMMs (unchanged from round 4/6).
// k_proj / k_final: LDS-staged weights + 4x4 register tiling (kills the
// VMEM-issue bottleneck measured in round 6: k_proj 345us @ 5% VALUBusy).

#define NN 20000
#define NE 200000
#define FD 132
#define RB 32
#define EVD 15
#define TE 64      // edges per block (200000 = 3125 * 64, exact)
#define KPAD 200   // HT LDS k-stride in bf16
#define KG 192     // global W2T k-stride
#define NP 144     // padded n (132 -> 9 tiles of 16)
#define PNT 28     // nodes per block in k_proj
#define FNT 28     // nodes per block in k_final

typedef __attribute__((ext_vector_type(8))) short bf16x8;
typedef __attribute__((ext_vector_type(4))) float f32x4;

__device__ __forceinline__ float silu_f(float x) {
    return x / (1.0f + __expf(-x));
}
__device__ __forceinline__ unsigned short f2bf(float x) {
    union { float f; unsigned u; } v; v.f = x;
    unsigned r = v.u + 0x7FFF + ((v.u >> 16) & 1);   // RNE
    return (unsigned short)(r >> 16);
}

// ---------------- prep: weight reshape/convert (idempotent, every call) ------
__global__ __launch_bounds__(256) void k_prep(
    const float* __restrict__ Wq, const float* __restrict__ Wk, const float* __restrict__ Wv,
    const float* __restrict__ fiW1, const float* __restrict__ fiW2, const float* __restrict__ fiWe2,
    const float* __restrict__ feW1, const float* __restrict__ feW2, const float* __restrict__ feWe2,
    unsigned short* __restrict__ W1Tfi, unsigned short* __restrict__ W1Tfe,
    unsigned short* __restrict__ W2Tfi, unsigned short* __restrict__ W2Tfe,
    float* __restrict__ WqP, float* __restrict__ WkP, float* __restrict__ WvP)
{
    const int gid = blockIdx.x * 256 + threadIdx.x;
    const int gs  = gridDim.x * 256;
    // W1T[n][k] (bf16, [144][32]) for MFMA B-operand
    for (int idx = gid; idx < NP * RB; idx += gs) {
        int n = idx / RB, k = idx - n * RB;
        W1Tfi[idx] = f2bf((n < FD) ? fiW1[k * FD + n] : 0.0f);
        W1Tfe[idx] = f2bf((n < FD) ? feW1[k * FD + n] : 0.0f);
    }
    // W2T[n][k] (bf16, [144][192]): k<132 from W2, 132<=k<165 from We2, else 0
    for (int idx = gid; idx < NP * KG; idx += gs) {
        int n = idx / KG, k = idx - n * KG;
        float vi = 0.0f, ve = 0.0f;
        if (n < FD) {
            if (k < FD)       { vi = fiW2[k * FD + n];          ve = feW2[k * FD + n]; }
            else if (k < 165) { vi = fiWe2[(k - FD) * FD + n];  ve = feWe2[(k - FD) * FD + n]; }
        }
        W2Tfi[idx] = f2bf(vi);
        W2Tfe[idx] = f2bf(ve);
    }
    // WqP/WkP/WvP [4][33][36] fp32: same layout as W, j padded 33->36 for b128
    for (int idx = gid; idx < 4 * 33 * 36; idx += gs) {
        int H = idx / (33 * 36), rem = idx - H * (33 * 36);
        int i = rem / 36, jp = rem - i * 36;
        float q = 0.f, k = 0.f, v = 0.f;
        if (jp < 33) {
            q = Wq[H * 1089 + i * 33 + jp];
            k = Wk[H * 1089 + i * 33 + jp];
            v = Wv[H * 1089 + i * 33 + jp];
        }
        WqP[idx] = q; WkP[idx] = k; WvP[idx] = v;
    }
}

// ---------------- node projections: LDS weights + 4x4 register tile ----------
__device__ __forceinline__ void proj_inv_pass(
    const float* __restrict__ wb, const float (*__restrict__ xT)[PNT],
    float* __restrict__ outp, int t, int n0)
{
    const int q = t % 36, g = t / 36;
    if (g >= 7) return;
    const int H = q / 9, jb = (q - H * 9) * 4, nb = g * 4;
    const int fb = H * 33;
    float acc[4][4] = {};
    for (int i = 0; i < 33; ++i) {
        const float4 w = *(const float4*)&wb[(fb + i) * 36 + jb];
        const float4 x = *(const float4*)&xT[fb + i][nb];
        const float xs[4] = {x.x, x.y, x.z, x.w};
        const float ws[4] = {w.x, w.y, w.z, w.w};
        #pragma unroll
        for (int r = 0; r < 4; ++r)
            #pragma unroll
            for (int c = 0; c < 4; ++c)
                acc[r][c] = fmaf(ws[c], xs[r], acc[r][c]);
    }
    #pragma unroll
    for (int c = 0; c < 4; ++c) {
        int jj = jb + c;
        if (jj >= 33) break;
        int j = H * 33 + jj;
        #pragma unroll
        for (int r = 0; r < 4; ++r) {
            int n = n0 + nb + r;
            if (n < NN) outp[n * FD + j] = acc[r][c];
        }
    }
}

__device__ __forceinline__ void proj_ev_pass(
    const float* __restrict__ wb, const float (*__restrict__ xT)[PNT],
    float* __restrict__ outp, int t, int n0)
{
    const int q = t % 33, g = t / 33;
    if (g >= 7) return;
    const int H = q / 11, jb = (q - H * 11) * 4, nb = g * 4;
    const int fb = H * 44;
    float acc[4][4] = {};
    for (int i = 0; i < 44; ++i) {
        const float4 w = *(const float4*)&wb[(fb + i) * 44 + jb];
        const float4 x = *(const float4*)&xT[fb + i][nb];
        const float xs[4] = {x.x, x.y, x.z, x.w};
        const float ws[4] = {w.x, w.y, w.z, w.w};
        #pragma unroll
        for (int r = 0; r < 4; ++r)
            #pragma unroll
            for (int c = 0; c < 4; ++c)
                acc[r][c] = fmaf(ws[c], xs[r], acc[r][c]);
    }
    #pragma unroll
    for (int c = 0; c < 4; ++c) {
        int j = fb + jb + c;
        #pragma unroll
        for (int r = 0; r < 4; ++r) {
            int n = n0 + nb + r;
            if (n < NN) outp[n * FD + j] = acc[r][c];
        }
    }
}

__global__ __launch_bounds__(256) void k_proj(
    const float* __restrict__ xin,
    const float* __restrict__ WqP, const float* __restrict__ WkP, const float* __restrict__ WvP,
    const float* __restrict__ Wqe, const float* __restrict__ Wke,
    float* __restrict__ qinv, float* __restrict__ kinv, float* __restrict__ vinv,
    float* __restrict__ qev, float* __restrict__ kev)
{
    __shared__ __align__(16) float xT[FD][PNT];   // 14.8 KB, transposed x tile
    __shared__ __align__(16) float wb[5808];      // 23.2 KB weight buffer
    const int t = threadIdx.x;
    const int n0 = blockIdx.x * PNT;

    for (int idx = t; idx < PNT * FD; idx += 256) {
        int nl = idx / FD, j = idx - nl * FD;
        int n = n0 + nl;
        xT[j][nl] = (n < NN) ? xin[n * FD + j] : 0.0f;
    }
    for (int idx = t; idx < 4752; idx += 256) wb[idx] = WqP[idx];
    __syncthreads();
    proj_inv_pass(wb, xT, qinv, t, n0);
    __syncthreads();
    for (int idx = t; idx < 4752; idx += 256) wb[idx] = WkP[idx];
    __syncthreads();
    proj_inv_pass(wb, xT, kinv, t, n0);
    __syncthreads();
    for (int idx = t; idx < 4752; idx += 256) wb[idx] = WvP[idx];
    __syncthreads();
    proj_inv_pass(wb, xT, vinv, t, n0);
    __syncthreads();
    for (int idx = t; idx < 5808; idx += 256) wb[idx] = Wqe[idx];
    __syncthreads();
    proj_ev_pass(wb, xT, qev, t, n0);
    __syncthreads();
    for (int idx = t; idx < 5808; idx += 256) wb[idx] = Wke[idx];
    __syncthreads();
    proj_ev_pass(wb, xT, kev, t, n0);
}

// ---------------- per-edge SO(3) invariants of ev-diff ------------------------
__global__ __launch_bounds__(256) void k_evi(
    const float* __restrict__ ev, const int* __restrict__ snd,
    const int* __restrict__ rcv, float* __restrict__ evi)
{
    int e = blockIdx.x * 256 + threadIdx.x;
    if (e >= NE) return;
    int s = snd[e], r = rcv[e];
    const float* ps = &ev[s * EVD];
    const float* pr = &ev[r * EVD];
    float s0 = 0.f, s1 = 0.f, s2 = 0.f;
    #pragma unroll
    for (int m = 0; m < 3; ++m)  { float d = ps[m] - pr[m]; s0 = fmaf(d, d, s0); }
    #pragma unroll
    for (int m = 3; m < 8; ++m)  { float d = ps[m] - pr[m]; s1 = fmaf(d, d, s1); }
    #pragma unroll
    for (int m = 8; m < 15; ++m) { float d = ps[m] - pr[m]; s2 = fmaf(d, d, s2); }
    evi[e * 3 + 0] = s0; evi[e * 3 + 1] = s1; evi[e * 3 + 2] = s2;
}

// ---------------- fused edge kernel: MFMA filter + attention + scatter --------
template<int PATH>
__global__ __launch_bounds__(256, 4) void k_edge(
    const float* __restrict__ rbf, const float* __restrict__ evi,
    const int* __restrict__ snd, const int* __restrict__ rcv,
    const float* __restrict__ cut, const float* __restrict__ sh,
    const unsigned short* __restrict__ W1T,  // [144][32] bf16
    const float* __restrict__ b1,
    const unsigned short* __restrict__ W2T,  // [144][192] bf16
    const float* __restrict__ b2,
    const float* __restrict__ We1, const float* __restrict__ be1,
    const float* __restrict__ be2,
    const float* __restrict__ qt, const float* __restrict__ kt,
    const float* __restrict__ vt, float* __restrict__ dout)
{
    // lds_buf: first holds HT [64][200] bf16 (25.6KB), then aliased FW [64][132] f32 (33.8KB)
    __shared__ __align__(16) char lds_buf[TE * FD * 4];
    __shared__ float evl[TE * 3];
    __shared__ int   sl[TE];
    __shared__ int   rl[TE];
    __shared__ float cl[TE];
    __shared__ float al[TE * 4];

    typedef unsigned short (*HTp)[KPAD];
    HTp HT   = (HTp)lds_buf;
    float* FW = (float*)lds_buf;

    const int t    = threadIdx.x;
    const int wv   = t >> 6;
    const int ln   = t & 63;
    const int lrow = ln & 15;    // A-row / B-col / D-col within tile
    const int kseg = ln >> 4;    // 0..3
    const int e0   = blockIdx.x * TE;

    if (t < TE) {
        sl[t] = snd[e0 + t];
        rl[t] = rcv[e0 + t];
        cl[t] = cut[e0 + t];
    }
    for (int idx = t; idx < TE * 3; idx += 256) evl[idx] = evi[e0 * 3 + idx];
    __syncthreads();

    // ---- H-GEMM: h = silu(rbf @ W1 + b1), one K=32 MFMA per n-tile ----
    {
        const int erow = e0 + 16 * wv + lrow;
        const float4 ra = *(const float4*)&rbf[erow * RB + kseg * 8];
        const float4 rb = *(const float4*)&rbf[erow * RB + kseg * 8 + 4];
        bf16x8 afrag;
        afrag[0] = (short)f2bf(ra.x); afrag[1] = (short)f2bf(ra.y);
        afrag[2] = (short)f2bf(ra.z); afrag[3] = (short)f2bf(ra.w);
        afrag[4] = (short)f2bf(rb.x); afrag[5] = (short)f2bf(rb.y);
        afrag[6] = (short)f2bf(rb.z); afrag[7] = (short)f2bf(rb.w);
        #pragma unroll
        for (int nt = 0; nt < 9; ++nt) {
            const int ncol = nt * 16 + lrow;
            bf16x8 bfrag = *(const bf16x8*)&W1T[ncol * RB + kseg * 8];
            f32x4 acc = {0.f, 0.f, 0.f, 0.f};
            acc = __builtin_amdgcn_mfma_f32_16x16x32_bf16(afrag, bfrag, acc, 0, 0, 0);
            if (ncol < FD) {
                const float bias = b1[ncol];
                #pragma unroll
                for (int r = 0; r < 4; ++r)
                    HT[16 * wv + kseg * 4 + r][ncol] = f2bf(silu_f(acc[r] + bias));
            }
        }
    }
    // g rows 132..164: silu(evi @ We1 + be1)
    for (int idx = t; idx < TE * 33; idx += 256) {
        int e = idx / 33, ii = idx - e * 33;
        float a = be1[ii];
        a = fmaf(evl[e * 3 + 0], We1[ii], a);
        a = fmaf(evl[e * 3 + 1], We1[33 + ii], a);
        a = fmaf(evl[e * 3 + 2], We1[66 + ii], a);
        HT[e][FD + ii] = f2bf(silu_f(a));
    }
    // zero-pad k 165..199
    for (int idx = t; idx < TE * (KPAD - 165); idx += 256) {
        int e = idx / (KPAD - 165), kk = idx - e * (KPAD - 165);
        HT[e][165 + kk] = 0;
    }
    __syncthreads();

    // ---- main GEMM: fw[64][132] = Hext[64][165] @ Wcat[165][132], bf16 MFMA ----
    f32x4 acc[9];
    #pragma unroll
    for (int nt = 0; nt < 9; ++nt) acc[nt] = (f32x4){0.f, 0.f, 0.f, 0.f};
    {
        const unsigned short* hrow = &HT[16 * wv + lrow][0];
        #pragma unroll
        for (int kt = 0; kt < 6; ++kt) {
            bf16x8 afrag = *(const bf16x8*)&hrow[kt * 32 + kseg * 8];
            #pragma unroll
            for (int nt = 0; nt < 9; ++nt) {
                bf16x8 bfrag = *(const bf16x8*)&W2T[(nt * 16 + lrow) * KG + kt * 32 + kseg * 8];
                acc[nt] = __builtin_amdgcn_mfma_f32_16x16x32_bf16(afrag, bfrag, acc[nt], 0, 0, 0);
            }
        }
    }
    __syncthreads();   // HT dead; safe to overwrite as FW

    #pragma unroll
    for (int nt = 0; nt < 9; ++nt) {
        const int ncol = nt * 16 + lrow;
        if (ncol < FD) {
            const float bias = b2[ncol] + be2[ncol];
            #pragma unroll
            for (int r = 0; r < 4; ++r)
                FW[(16 * wv + kseg * 4 + r) * FD + ncol] = acc[nt][r] + bias;
        }
    }
    __syncthreads();

    // ---- qk products in place: FW[e][j] *= q[rcv][j] * k[snd][j] ----
    for (int idx = t; idx < TE * FD; idx += 256) {
        int e = idx / FD, j = idx - e * FD;
        FW[idx] *= qt[rl[e] * FD + j] * kt[sl[e] * FD + j];
    }
    __syncthreads();

    // ---- per-(edge,head) sums; cutoff & 1/sqrt(D) folded in ----
    if (PATH == 0) {
        {   // 256 threads = 64 edges x 4 heads, exact
            int e = t >> 2, H = t & 3;
            const float* fp = &FW[e * FD + H * 33];
            float a = 0.0f;
            #pragma unroll
            for (int j = 0; j < 33; ++j) a += fp[j];
            al[t] = a * cl[e] * 0.17407765595569785f;  // cutoff / sqrt(33)
        }
    } else {
        if (t < TE * 3) {
            int e = t / 3, H = t - e * 3;
            const float* fp = &FW[e * FD + H * 44];
            float a = 0.0f;
            #pragma unroll
            for (int j = 0; j < 44; ++j) a += fp[j];
            al[e * 4 + H] = a * cl[e] * 0.15075567228888181f;  // cutoff / sqrt(44)
        }
    }
    __syncthreads();

    // ---- scatter ----
    if (PATH == 0) {
        for (int idx = t; idx < TE * FD; idx += 256) {
            int e = idx / FD, j = idx - e * FD;
            float v = al[e * 4 + j / 33] * vt[sl[e] * FD + j];
            atomicAdd(&dout[rl[e] * FD + j], v);
        }
    } else {
        for (int idx = t; idx < TE * EVD; idx += 256) {
            int e = idx / EVD, m = idx - e * EVD;
            int hd = (m < 3) ? 0 : ((m < 8) ? 1 : 2);
            float v = al[e * 4 + hd] * sh[(e0 + e) * EVD + m];
            atomicAdd(&dout[rl[e] * EVD + m], v);
        }
    }
}

// ---------------- final node update: LDS Wint chunks + 4x4 register tile -----
__global__ __launch_bounds__(256) void k_final(
    const float* __restrict__ xin, const float* __restrict__ evf,
    const float* __restrict__ dinv, const float* __restrict__ dev,
    const float* __restrict__ Wint, const float* __restrict__ bint,
    float* __restrict__ out)
{
    __shared__ __align__(16) float catT[136][FNT];  // 15.2 KB, c-major cat tile
    __shared__ __align__(16) float wb[45 * 136];    // 24.5 KB Wint row chunk
    __shared__ float aev[FNT][16];
    __shared__ float tacc[FNT][4];
    const int t = threadIdx.x;
    const int n0 = blockIdx.x * FNT;

    for (int idx = t; idx < FNT * FD; idx += 256) {
        int nl = idx / FD, j = idx - nl * FD;
        int n = n0 + nl;
        catT[j][nl] = (n < NN) ? xin[n * FD + j] + dinv[n * FD + j] : 0.0f;
    }
    for (int idx = t; idx < FNT * EVD; idx += 256) {
        int nl = idx / EVD, m = idx - nl * EVD;
        int n = n0 + nl;
        aev[nl][m] = (n < NN) ? evf[n * EVD + m] + dev[n * EVD + m] : 0.0f;
    }
    if (t < FNT) catT[135][t] = 0.0f;
    __syncthreads();
    if (t < FNT * 3) {
        int nl = t / 3, k = t - nl * 3;
        int lo = (k == 0) ? 0 : ((k == 1) ? 3 : 8);
        int hi = (k == 0) ? 3 : ((k == 1) ? 8 : 15);
        float s = 0.f;
        for (int m = lo; m < hi; ++m) { float v = aev[nl][m]; s = fmaf(v, v, s); }
        catT[FD + k][nl] = s;
    }

    const int q = t % 34, g = t / 34;
    const int jb = q * 4, nb = g * 4;
    const bool act = (g < 7);
    float acc[4][4] = {};
    for (int ch = 0; ch < 3; ++ch) {
        __syncthreads();   // prior chunk reads (and, ch=0, evi2 writes) done
        const int rbase = ch * 45;
        for (int idx = t; idx < 45 * 136; idx += 256) {
            int r = idx / 136, j = idx - r * 136;
            wb[idx] = (j < 135) ? Wint[(rbase + r) * 135 + j] : 0.0f;
        }
        __syncthreads();
        if (act) {
            for (int c = 0; c < 45; ++c) {
                const float4 w = *(const float4*)&wb[c * 136 + jb];
                const float4 x = *(const float4*)&catT[rbase + c][nb];
                const float xs[4] = {x.x, x.y, x.z, x.w};
                const float ws[4] = {w.x, w.y, w.z, w.w};
                #pragma unroll
                for (int r = 0; r < 4; ++r)
                    #pragma unroll
                    for (int cc = 0; cc < 4; ++cc)
                        acc[r][cc] = fmaf(ws[cc], xs[r], acc[r][cc]);
            }
        }
    }
    if (act) {
        #pragma unroll
        for (int c = 0; c < 4; ++c) {
            int j = jb + c;
            if (j >= 135) break;
            float bj = bint[j];
            #pragma unroll
            for (int r = 0; r < 4; ++r) {
                int n = n0 + nb + r;
                if (n >= NN) continue;
                float a = acc[r][c] + bj;
                if (j < FD) out[n * FD + j] = catT[j][nb + r] + a;  // att_inv + d_inv2
                else        tacc[nb + r][j - FD] = a;               // b_ev
            }
        }
    }
    __syncthreads();
    for (int idx = t; idx < FNT * EVD; idx += 256) {
        int nl = idx / EVD, m = idx - nl * EVD;
        int n = n0 + nl;
        if (n >= NN) continue;
        int hd = (m < 3) ? 0 : ((m < 8) ? 1 : 2);
        out[NN * FD + n * EVD + m] = aev[nl][m] * (1.0f + tacc[nl][hd]);
    }
}

extern "C" void kernel_launch(void* const* d_in, const int* in_sizes, int n_in,
                              void* d_out, int out_size, void* d_ws, size_t ws_size,
                              hipStream_t stream)
{
    (void)in_sizes; (void)n_in; (void)out_size; (void)ws_size;
    const float* xin  = (const float*)d_in[0];
    const float* evf  = (const float*)d_in[1];
    const float* rbf  = (const float*)d_in[2];
    const int*   snd  = (const int*)d_in[3];
    const int*   rcv  = (const int*)d_in[4];
    const float* sh   = (const float*)d_in[5];
    const float* cut  = (const float*)d_in[6];
    const float* Wint = (const float*)d_in[28];
    const float* bint = (const float*)d_in[29];

    float* ws   = (float*)d_ws;
    float* qinv = ws;                       // NN*FD
    float* kinv = qinv + NN * FD;
    float* vinv = kinv + NN * FD;
    float* qev  = vinv + NN * FD;
    float* kev  = qev  + NN * FD;
    float* evi  = kev  + NN * FD;           // NE*3
    float* dinv = evi  + NE * 3;            // NN*FD
    float* dev  = dinv + NN * FD;           // NN*EVD
    float* wtail = dev + NN * EVD;          // prep region (16B-aligned)

    unsigned short* W2Tfi = (unsigned short*)wtail;        // 27648 bf16
    unsigned short* W2Tfe = W2Tfi + NP * KG;               // 27648
    unsigned short* W1Tfi = W2Tfe + NP * KG;               // 4608
    unsigned short* W1Tfe = W1Tfi + NP * RB;               // 4608
    float* WqP = (float*)(W1Tfe + NP * RB);                // 4752 f32 each
    float* WkP = WqP + 4 * 33 * 36;
    float* WvP = WkP + 4 * 33 * 36;

    hipMemsetAsync(dinv, 0, (size_t)(NN * FD + NN * EVD) * sizeof(float), stream);

    k_prep<<<64, 256, 0, stream>>>(
        (const float*)d_in[7], (const float*)d_in[8], (const float*)d_in[9],
        (const float*)d_in[12], (const float*)d_in[14], (const float*)d_in[18],
        (const float*)d_in[20], (const float*)d_in[22], (const float*)d_in[26],
        W1Tfi, W1Tfe, W2Tfi, W2Tfe, WqP, WkP, WvP);

    k_proj<<<(NN + PNT - 1) / PNT, 256, 0, stream>>>(
        xin, WqP, WkP, WvP,
        (const float*)d_in[10], (const float*)d_in[11],
        qinv, kinv, vinv, qev, kev);
    k_evi<<<(NE + 255) / 256, 256, 0, stream>>>(evf, snd, rcv, evi);

    const int nt = NE / TE;  // 3125, exact
    k_edge<0><<<nt, 256, 0, stream>>>(rbf, evi, snd, rcv, cut, sh,
        W1Tfi, (const float*)d_in[13], W2Tfi, (const float*)d_in[15],
        (const float*)d_in[16], (const float*)d_in[17], (const float*)d_in[19],
        qinv, kinv, vinv, dinv);
    k_edge<1><<<nt, 256, 0, stream>>>(rbf, evi, snd, rcv, cut, sh,
        W1Tfe, (const float*)d_in[21], W2Tfe, (const float*)d_in[23],
        (const float*)d_in[24], (const float*)d_in[25], (const float*)d_in[27],
        qev, kev, nullptr, dev);

    k_final<<<(NN + FNT - 1) / FNT, 256, 0, stream>>>(
        xin, evf, dinv, dev, Wint, bint, (float*)d_out);
}